// Round 10
// baseline (699.407 us; speedup 1.0000x reference)
//
#include <hip/hip_runtime.h>
#include <hip/hip_bf16.h>

namespace {
constexpr int kNA = 4353, kNM = 3676, kNT = 8000;
constexpr int kN  = kNA + kNM + kNT;      // 16029
constexpr int kE  = 500000;
constexpr int kS  = 200000;
constexpr int kDIN = 512, kDP = 256, kDE = 128, kDC = 64;

constexpr size_t OUT_X  = (size_t)kN * kDE;            // h first
constexpr size_t OUT_HM = OUT_X + 3ull * kS;           // then x, then h_movie

constexpr size_t align256(size_t x) { return (x + 255) & ~size_t(255); }

// float-tensor table (d_in indices 0..18): cumulative element offsets
constexpr int kNF = 19;
constexpr int kFOff[kNF + 1] = {
    0, 2228736, 4110848, 8206848, 8337920, 8468992, 8600064, 8632832, 8632960,
    8649344, 8649472, 8657664, 8665856, 8674048, 8678144, 8682240, 8686336,
    8686352, 8686368, 8686384 };
constexpr int kTotF = 8686384;

// int-tensor table (d_in indices 19..29): cumulative element offsets
constexpr int kNI = 11;
constexpr int kIOff[kNI + 1] = {
    0, 500000, 1000000, 1200000, 1400000, 1600000, 1800000, 2000000,
    2200000, 2400000, 2600000, 2800000 };
constexpr int kTotI = 2800000;

// offsets inside canonical f32 buffer AF (elements)
constexpr int A_WPA = 8206848, A_WPM = 8337920, A_WPT = 8468992;
constexpr int A_W1  = 8600064, A_B1  = 8632832, A_W2  = 8632960, A_B2 = 8649344;
constexpr int A_WCA = 8649472, A_WCM = 8657664, A_WCT = 8665856;
constexpr int A_WH  = 8674048;   // 3 x 4096 contiguous
constexpr int A_WO  = 8686336;   // 3 x 16 contiguous

// ---- workspace layout (~64 MB peak, proven available) ----
constexpr size_t OFF_FLAGF = 0;     // 19 ints
constexpr size_t OFF_FLAGI = 96;    // 11 ints
constexpr size_t OFF_AF    = 256;
constexpr size_t OFF_H     = align256(OFF_AF + (size_t)kTotF * 4);
constexpr size_t OFF_IC    = align256(OFF_H + (size_t)kN * kDP * 4);
constexpr size_t OFF_ESRC  = align256(OFF_IC + (size_t)kTotI * 4);
constexpr size_t OFF_RP    = align256(OFF_ESRC + (size_t)kE * 4);
constexpr size_t OFF_CUR   = align256(OFF_RP + (size_t)(kN + 1) * 4);
constexpr size_t WS_NEEDED = align256(OFF_CUR + (size_t)kN * 4);
// lifetime overlays:
//   AF's feature part (kN*kDIN = 32.8 MB) dead after proj -> agg1, h1, c_all
//   H (16.4 MB) dead after agg1 -> agg2, hn
constexpr size_t OFF_AGG1  = OFF_AF;
constexpr size_t OFF_H1    = OFF_AF + (size_t)kN * kDP * 4;
constexpr size_t OFF_AGG2  = OFF_H;
constexpr size_t OFF_HN    = OFF_H + (size_t)kN * kDE * 4;
constexpr size_t OFF_C     = OFF_AF;
} // namespace

struct PtrsF { const void* p[19]; };
struct PtrsI { const void* p[11]; };

// ---- per-tensor dtype probe (all-f32 / all-int32 proven on this rig; kept
// as cheap insurance so data reads stay measured, not assumed) ----
__global__ __launch_bounds__(256) void detect_all_kernel(PtrsF pf, PtrsI pi,
                                                         int* __restrict__ flagF,
                                                         int* __restrict__ flagI)
{
    __shared__ int shZ[256];
    __shared__ int shS[256];
    int b = blockIdx.x, tid = threadIdx.x;
    int zc = 0, sc = 0, K = 0;
    if (b < kNF) {
        int n = kFOff[b + 1] - kFOff[b];
        int Khw = min(n, 1024);
        K = (Khw + 1) >> 1;
        const unsigned short* u = (const unsigned short*)pf.p[b];
        for (int i = tid; i < K; i += 256) {
            unsigned v = u[2 * i];
            if (v == 0u) zc++;
            else {
                float a = fabsf(__uint_as_float(v << 16));
                if (a >= 0.0009765625f && a <= 64.f) sc++;
            }
        }
    } else {
        int j = b - kNF;
        int n = kIOff[j + 1] - kIOff[j];
        K = min(n / 2, 512);
        const unsigned* u = (const unsigned*)pi.p[j];
        for (int i = tid; i < K; i += 256)
            if (u[2 * i + 1] == 0u) zc++;
    }
    shZ[tid] = zc; shS[tid] = sc;
    __syncthreads();
    for (int s = 128; s > 0; s >>= 1) {
        if (tid < s) { shZ[tid] += shZ[tid + s]; shS[tid] += shS[tid + s]; }
        __syncthreads();
    }
    if (tid == 0) {
        if (b < kNF) {
            int z = shZ[0], sn = shS[0];
            int f;
            if (z * 10 >= K * 9)       f = 0;    // bf16-rounded f32 (or zeros) -> f32 read
            else if (sn * 10 >= K * 8) f = 1;    // true bf16 buffer
            else                       f = 0;    // plain f32
            flagF[b] = f;
        } else {
            flagI[b - kNF] = (shZ[0] * 10 >= K * 9) ? 1 : 0;   // int64
        }
    }
}

// ---- materialize all float inputs as canonical f32 ----
__global__ __launch_bounds__(256) void cvt_float_kernel(PtrsF in, const int* __restrict__ flagF,
                                                        float* __restrict__ AF)
{
    int t = blockIdx.x * 256 + threadIdx.x;
    if (t >= kTotF) return;
    int lo = 0, hi = kNF;
    while (hi - lo > 1) { int mid = (lo + hi) >> 1; if (t >= kFOff[mid]) lo = mid; else hi = mid; }
    int j = t - kFOff[lo];
    float v;
    if (flagF[lo]) v = __uint_as_float(((unsigned)((const unsigned short*)in.p[lo])[j]) << 16);
    else           v = ((const float*)in.p[lo])[j];
    AF[t] = v;
}

// ---- materialize all int inputs as canonical int32 ----
__global__ __launch_bounds__(256) void cvt_int_kernel(PtrsI in, const int* __restrict__ flagI,
                                                      int* __restrict__ IC)
{
    int t = blockIdx.x * 256 + threadIdx.x;
    if (t >= kTotI) return;
    int lo = 0, hi = kNI;
    while (hi - lo > 1) { int mid = (lo + hi) >> 1; if (t >= kIOff[mid]) lo = mid; else hi = mid; }
    int j = t - kIOff[lo];
    const int* p = (const int*)in.p[lo];
    IC[t] = flagI[lo] ? p[2 * j] : p[j];
}

// ---- projection: H[n] = feat[n] @ Wp_type(n); 8 rows/block x 256 cols ----
__global__ __launch_bounds__(256) void proj_kernel(const float* __restrict__ AF,
                                                   float* __restrict__ H,
                                                   int nAblk, int nMblk)
{
    int b = blockIdx.x;
    const float* W; int typeN, rowBase, lb;
    if (b < nAblk)              { lb = b;                 W = AF + A_WPA; typeN = kNA; rowBase = 0; }
    else if (b < nAblk + nMblk) { lb = b - nAblk;         W = AF + A_WPM; typeN = kNM; rowBase = kNA; }
    else                        { lb = b - nAblk - nMblk; W = AF + A_WPT; typeN = kNT; rowBase = kNA + kNM; }
    int r0 = lb * 8, col = threadIdx.x;
    float acc[8];
#pragma unroll
    for (int r = 0; r < 8; r++) acc[r] = 0.f;
    for (int k = 0; k < kDIN; k += 4) {
        float b0 = W[(k + 0) * kDP + col];
        float b1 = W[(k + 1) * kDP + col];
        float b2 = W[(k + 2) * kDP + col];
        float b3 = W[(k + 3) * kDP + col];
#pragma unroll
        for (int r = 0; r < 8; r++) {
            int gr = min(r0 + r, typeN - 1);                  // uniform -> scalar load
            const float4 a4 = *(const float4*)(AF + (size_t)(rowBase + gr) * kDIN + k);
            acc[r] += a4.x * b0 + a4.y * b1 + a4.z * b2 + a4.w * b3;
        }
    }
#pragma unroll
    for (int r = 0; r < 8; r++) {
        int lr = r0 + r;
        if (lr < typeN) H[(size_t)(rowBase + lr) * kDP + col] = acc[r];
    }
}

// ---- CSR build (indices clamped for memory safety) ----
__device__ __forceinline__ int clampN(int v) { return min(max(v, 0), kN - 1); }

__global__ __launch_bounds__(256) void hist_kernel(const int* __restrict__ key,
                                                   int* __restrict__ counts)
{
    int e = blockIdx.x * 256 + threadIdx.x;
    if (e < kE) atomicAdd(&counts[clampN(key[e])], 1);
}

__global__ __launch_bounds__(256) void scan_kernel(int* __restrict__ cnt_cur,
                                                   int* __restrict__ rowptr)
{
    __shared__ int sums[256];
    int tid = threadIdx.x;
    int i0 = tid * 63, i1 = min(i0 + 63, kN);
    int s = 0;
    for (int i = i0; i < i1; i++) s += cnt_cur[i];
    sums[tid] = s;
    __syncthreads();
    if (tid == 0) {
        int run = 0;
        for (int i = 0; i < 256; i++) { int v = sums[i]; sums[i] = run; run += v; }
    }
    __syncthreads();
    int base = sums[tid];
    for (int i = i0; i < i1; i++) {
        int c = cnt_cur[i];
        rowptr[i] = base;
        cnt_cur[i] = base;       // becomes the fill cursor
        base += c;
    }
    if (tid == 0) rowptr[kN] = kE;
}

__global__ __launch_bounds__(256) void fill_kernel(const int* __restrict__ stored,
                                                   const int* __restrict__ key,
                                                   int* __restrict__ cursor,
                                                   int* __restrict__ esrc)
{
    int e = blockIdx.x * 256 + threadIdx.x;
    if (e < kE) {
        int p = atomicAdd(&cursor[clampN(key[e])], 1);
        esrc[min(p, kE - 1)] = clampN(stored[e]);
    }
}

// ---- CSR aggregation: out[n] = sum_{e: key==n} X[stored[e]] ----
template <int D>
__global__ __launch_bounds__(D) void agg_kernel(const float* __restrict__ X,
                                                const int* __restrict__ rowptr,
                                                const int* __restrict__ esrc,
                                                float* __restrict__ out)
{
    int n = blockIdx.x;
    int tid = threadIdx.x;
    int j = rowptr[n], end = rowptr[n + 1];
    float acc0 = 0.f, acc1 = 0.f;
    for (; j + 1 < end; j += 2) {
        int s0 = esrc[j], s1 = esrc[j + 1];
        acc0 += X[(size_t)s0 * D + tid];
        acc1 += X[(size_t)s1 * D + tid];
    }
    if (j < end) acc0 += X[(size_t)esrc[j] * D + tid];
    out[(size_t)n * D + tid] = acc0 + acc1;
}

// ---- dense GEMM + bias (+relu): out[N x COLS] = X[N x K] @ W + b ----
template <int K, int COLS, bool RELU>
__global__ __launch_bounds__(COLS) void gemm_bias_kernel(
    const float* __restrict__ X, const float* __restrict__ W,
    const float* __restrict__ bias, float* __restrict__ out)
{
    int r0 = blockIdx.x * 8;
    int col = threadIdx.x;
    float acc[8];
#pragma unroll
    for (int r = 0; r < 8; r++) acc[r] = 0.f;
    for (int k = 0; k < K; k += 4) {
        float b0 = W[(k + 0) * COLS + col];
        float b1 = W[(k + 1) * COLS + col];
        float b2 = W[(k + 2) * COLS + col];
        float b3 = W[(k + 3) * COLS + col];
#pragma unroll
        for (int r = 0; r < 8; r++) {
            int gr = min(r0 + r, kN - 1);                     // uniform -> scalar load
            const float4 a4 = *(const float4*)(X + (size_t)gr * K + k);
            acc[r] += a4.x * b0 + a4.y * b1 + a4.z * b2 + a4.w * b3;
        }
    }
    float bv = bias[col];
#pragma unroll
    for (int r = 0; r < 8; r++) {
        int gr = r0 + r;
        if (gr < kN) {
            float v = acc[r] + bv;
            if (RELU) v = fmaxf(v, 0.f);
            out[(size_t)gr * COLS + col] = v;
        }
    }
}

// ---- row L2-normalize; write h (f32 OUT) and h_movie slice (f32 OUT) ----
__global__ __launch_bounds__(kDE) void norm_kernel(float* __restrict__ h2,
                                                   float* __restrict__ out)
{
    int n = blockIdx.x, tid = threadIdx.x;
    float v = h2[(size_t)n * kDE + tid];
    float ss = v * v;
#pragma unroll
    for (int o = 32; o > 0; o >>= 1) ss += __shfl_xor(ss, o);
    __shared__ float wsum[2];
    if ((tid & 63) == 0) wsum[tid >> 6] = ss;
    __syncthreads();
    float tot = wsum[0] + wsum[1];
    float sc = 1.f / fmaxf(sqrtf(tot), 1e-12f);
    float hv = v * sc;
    h2[(size_t)n * kDE + tid] = hv;
    out[(size_t)n * kDE + tid] = hv;
    if (n >= kNA && n < kNA + kNM)
        out[OUT_HM + (size_t)(n - kNA) * kDE + tid] = hv;
}

// ---- per-type context projections: c_all[n] = hn[n] @ Wc_type(n) ----
__global__ __launch_bounds__(64) void wc_kernel(const float* __restrict__ hn,
                                                const float* __restrict__ AF,
                                                float* __restrict__ c_all,
                                                int nAblk, int nMblk)
{
    int b = blockIdx.x;
    const float* W; int typeN, rowBase, lb;
    if (b < nAblk)              { lb = b;                 W = AF + A_WCA; typeN = kNA; rowBase = 0; }
    else if (b < nAblk + nMblk) { lb = b - nAblk;         W = AF + A_WCM; typeN = kNM; rowBase = kNA; }
    else                        { lb = b - nAblk - nMblk; W = AF + A_WCT; typeN = kNT; rowBase = kNA + kNM; }
    int r0 = lb * 8, col = threadIdx.x;
    float acc[8];
#pragma unroll
    for (int r = 0; r < 8; r++) acc[r] = 0.f;
    for (int k = 0; k < kDE; k += 4) {
        float b0 = W[(k + 0) * kDC + col];
        float b1 = W[(k + 1) * kDC + col];
        float b2 = W[(k + 2) * kDC + col];
        float b3 = W[(k + 3) * kDC + col];
#pragma unroll
        for (int r = 0; r < 8; r++) {
            int gr = min(r0 + r, typeN - 1);
            const float4 a4 = *(const float4*)(hn + (size_t)(rowBase + gr) * kDE + k);
            acc[r] += a4.x * b0 + a4.y * b1 + a4.z * b2 + a4.w * b3;
        }
    }
#pragma unroll
    for (int r = 0; r < 8; r++) {
        int lr = r0 + r;
        if (lr < typeN) c_all[(size_t)(rowBase + lr) * kDC + col] = acc[r];
    }
}

// ---- classifier: x = sigmoid(relu(feat @ Wh) @ Wo), thread-per-sample ----
__global__ __launch_bounds__(256) void cls_kernel(
    const float* __restrict__ hn, const float* __restrict__ c_all,
    const float* __restrict__ AF, const int* __restrict__ IC,
    float* __restrict__ out, int blocksPerGroup)
{
    int g = blockIdx.x / blocksPerGroup;
    int i = (blockIdx.x % blocksPerGroup) * 256 + threadIdx.x;
    if (i >= kS) return;
    const int* n0a = IC + 1000000; const int* n0m = IC + 1200000; const int* n0t = IC + 1400000;
    const int* n1a = IC + 1600000; const int* n1m = IC + 1800000; const int* n1t = IC + 2000000;
    const int* n2a = IC + 2200000; const int* n2m = IC + 2400000; const int* n2t = IC + 2600000;
    auto cA = [](int v){ return min(max(v, 0), kNA - 1); };
    auto cM = [](int v){ return min(max(v, 0), kNM - 1); };
    auto cT = [](int v){ return min(max(v, 0), kNT - 1); };
    int rA, r1, r2;
    if (g == 0)      { rA = cA(n0a[i]);             r1 = kNA + cM(n0m[i]);  r2 = kNA + kNM + cT(n0t[i]); }
    else if (g == 1) { rA = kNA + cM(n1m[i]);       r1 = cA(n1a[i]);        r2 = kNA + kNM + cT(n1t[i]); }
    else             { rA = kNA + kNM + cT(n2t[i]); r1 = cA(n2a[i]);        r2 = kNA + cM(n2m[i]); }
    const float4* fa = (const float4*)(hn + (size_t)rA * kDE);
    const float4* f1 = (const float4*)(c_all + (size_t)r1 * kDC);
    const float4* f2 = (const float4*)(c_all + (size_t)r2 * kDC);
    const float* Whg = AF + A_WH + g * 4096;    // uniform -> SGPR broadcast
    float acc[16];
#pragma unroll
    for (int j = 0; j < 16; j++) acc[j] = 0.f;
    for (int k4 = 0; k4 < 32; k4++) {           // hn part: k = 0..127
        float4 f = fa[k4];
        const float* w = Whg + k4 * 64;
#pragma unroll
        for (int j = 0; j < 16; j++)
            acc[j] += f.x * w[j] + f.y * w[j + 16] + f.z * w[j + 32] + f.w * w[j + 48];
    }
    for (int k4 = 0; k4 < 16; k4++) {           // c1 part: k = 128..191
        float4 f = f1[k4];
        const float* w = Whg + 2048 + k4 * 64;
#pragma unroll
        for (int j = 0; j < 16; j++)
            acc[j] += f.x * w[j] + f.y * w[j + 16] + f.z * w[j + 32] + f.w * w[j + 48];
    }
    for (int k4 = 0; k4 < 16; k4++) {           // c2 part: k = 192..255
        float4 f = f2[k4];
        const float* w = Whg + 3072 + k4 * 64;
#pragma unroll
        for (int j = 0; j < 16; j++)
            acc[j] += f.x * w[j] + f.y * w[j + 16] + f.z * w[j + 32] + f.w * w[j + 48];
    }
    const float* wo = AF + A_WO + g * 16;
    float p = 0.f;
#pragma unroll
    for (int j = 0; j < 16; j++) p += fmaxf(acc[j], 0.f) * wo[j];
    out[OUT_X + (size_t)g * kS + i] = 1.f / (1.f + expf(-p));
}

extern "C" void kernel_launch(void* const* d_in, const int* in_sizes, int n_in,
                              void* d_out, int out_size, void* d_ws, size_t ws_size,
                              hipStream_t stream)
{
    (void)out_size;
    // canary: verify input ordering/sizes; if wrong, launch nothing (stub signature)
    static const int expected[30] = {
        2228736, 1882112, 4096000, 131072, 131072, 131072, 32768, 128, 16384, 128,
        8192, 8192, 8192, 4096, 4096, 4096, 16, 16, 16,
        500000, 500000, 200000, 200000, 200000, 200000, 200000, 200000, 200000, 200000, 200000 };
    if (n_in != 30) return;
    for (int i = 0; i < 30; i++) if (in_sizes[i] != expected[i]) return;
    if (ws_size < WS_NEEDED) return;

    char* ws = (char*)d_ws;
    int*   flagF  = (int*)(ws + OFF_FLAGF);
    int*   flagI  = (int*)(ws + OFF_FLAGI);
    float* AF     = (float*)(ws + OFF_AF);
    float* H      = (float*)(ws + OFF_H);
    int*   IC     = (int*)(ws + OFF_IC);
    float* agg1   = (float*)(ws + OFF_AGG1);
    float* h1     = (float*)(ws + OFF_H1);
    float* agg2   = (float*)(ws + OFF_AGG2);
    float* hn     = (float*)(ws + OFF_HN);
    float* c_all  = (float*)(ws + OFF_C);
    int* rowptr   = (int*)(ws + OFF_RP);
    int* cursor   = (int*)(ws + OFF_CUR);
    int* esrc     = (int*)(ws + OFF_ESRC);
    float* out    = (float*)d_out;             // OUTPUT IS FLOAT32 (proven r9)

    PtrsF pf; for (int i = 0; i < 19; i++) pf.p[i] = d_in[i];
    PtrsI pi; for (int i = 0; i < 11; i++) pi.p[i] = d_in[19 + i];
    const int* srcC = IC;
    const int* dstC = IC + 500000;

    hipMemsetAsync(cursor, 0, (size_t)kN * 4, stream);

    detect_all_kernel<<<dim3(30), dim3(256), 0, stream>>>(pf, pi, flagF, flagI);
    cvt_float_kernel<<<dim3(33932), dim3(256), 0, stream>>>(pf, flagF, AF);
    cvt_int_kernel<<<dim3(10938), dim3(256), 0, stream>>>(pi, flagI, IC);

    // reference direction: out[dst[e]] += X[src[e]]
    hist_kernel<<<dim3(1954), dim3(256), 0, stream>>>(dstC, cursor);
    scan_kernel<<<dim3(1), dim3(256), 0, stream>>>(cursor, rowptr);
    fill_kernel<<<dim3(1954), dim3(256), 0, stream>>>(srcC, dstC, cursor, esrc);

    proj_kernel<<<dim3(2005), dim3(256), 0, stream>>>(AF, H, 545, 460);
    agg_kernel<kDP><<<dim3(kN), dim3(kDP), 0, stream>>>(H, rowptr, esrc, agg1);
    gemm_bias_kernel<kDP, kDE, true><<<dim3(2004), dim3(kDE), 0, stream>>>(agg1, AF + A_W1, AF + A_B1, h1);
    agg_kernel<kDE><<<dim3(kN), dim3(kDE), 0, stream>>>(h1, rowptr, esrc, agg2);
    gemm_bias_kernel<kDE, kDE, false><<<dim3(2004), dim3(kDE), 0, stream>>>(agg2, AF + A_W2, AF + A_B2, hn);
    norm_kernel<<<dim3(kN), dim3(kDE), 0, stream>>>(hn, out);
    wc_kernel<<<dim3(2005), dim3(64), 0, stream>>>(hn, AF, c_all, 545, 460);
    cls_kernel<<<dim3(2346), dim3(256), 0, stream>>>(hn, c_all, AF, IC, out, 782);
}

// Round 11
// 364.581 us; speedup vs baseline: 1.9184x; 1.9184x over previous
//
#include <hip/hip_runtime.h>
#include <hip/hip_bf16.h>

namespace {
constexpr int kNA = 4353, kNM = 3676, kNT = 8000;
constexpr int kN  = kNA + kNM + kNT;      // 16029
constexpr int kE  = 500000;
constexpr int kS  = 200000;
constexpr int kDIN = 512, kDP = 256, kDE = 128, kDC = 64;

constexpr size_t OUT_X  = (size_t)kN * kDE;            // h first
constexpr size_t OUT_HM = OUT_X + 3ull * kS;           // then x, then h_movie

constexpr size_t align256(size_t x) { return (x + 255) & ~size_t(255); }

// ---- workspace layout (~39 MB peak; 64 MB proven available) ----
constexpr size_t OFF_WPW1 = 0;                                   // 3 x 512 x 128 f32
constexpr size_t OFF_M9   = OFF_WPW1 + 3ull * 512 * 128 * 4;     // 9 x 128 x 16 f32
constexpr size_t OFF_HW1  = align256(OFF_M9 + 9ull * 2048 * 4);  // kN x 128
constexpr size_t OFF_H1   = OFF_HW1 + (size_t)kN * kDE * 4;      // kN x 128
constexpr size_t OFF_AGG2 = OFF_H1  + (size_t)kN * kDE * 4;      // kN x 128
constexpr size_t OFF_HN   = OFF_AGG2 + (size_t)kN * kDE * 4;     // kN x 128
constexpr size_t OFF_P    = OFF_HN  + (size_t)kN * kDE * 4;      // 3 x kN x 16
constexpr size_t OFF_ESRC = align256(OFF_P + 3ull * kN * 16 * 4);
constexpr size_t OFF_RP   = align256(OFF_ESRC + (size_t)kE * 4);
constexpr size_t OFF_CUR  = align256(OFF_RP + (size_t)(kN + 1) * 4);
constexpr size_t WS_NEEDED = align256(OFF_CUR + (size_t)kN * 4);
} // namespace

// ---- prep1: WpW1[t] = Wp_t (512x256) @ W1 (256x128), 4 rows/block ----
__global__ __launch_bounds__(128) void prep1_kernel(
    const float* __restrict__ WpA, const float* __restrict__ WpM,
    const float* __restrict__ WpT, const float* __restrict__ W1,
    float* __restrict__ WpW1)
{
    int b = blockIdx.x;               // 0..383
    int t = b >> 7;
    int k0 = (b & 127) * 4;
    const float* Wp = (t == 0) ? WpA : ((t == 1) ? WpM : WpT);
    int c = threadIdx.x;
    float acc[4] = {0.f, 0.f, 0.f, 0.f};
    for (int j = 0; j < kDP; j++) {
        float w1 = W1[j * kDE + c];
#pragma unroll
        for (int r = 0; r < 4; r++)
            acc[r] += Wp[(k0 + r) * kDP + j] * w1;       // uniform -> s_load
    }
#pragma unroll
    for (int r = 0; r < 4; r++)
        WpW1[((size_t)t * kDIN + k0 + r) * kDE + c] = acc[r];
}

// ---- prep2: M9[g][t] (128x16) = Wh_g[0:128] (primary) or Wc_t @ Wh_g[slot:slot+64] ----
// concat slots: g0=[hA,cM,cT], g1=[hM,cA,cT], g2=[hT,cA,cM]
__global__ __launch_bounds__(256) void prep2_kernel(
    const float* __restrict__ WhA, const float* __restrict__ WhM,
    const float* __restrict__ WhT,
    const float* __restrict__ WcA, const float* __restrict__ WcM,
    const float* __restrict__ WcT,
    float* __restrict__ M9)
{
    int b = blockIdx.x;               // 0..8
    int g = b / 3, t = b % 3;
    const float* Wh = (g == 0) ? WhA : ((g == 1) ? WhM : WhT);
    const float* Wc = (t == 0) ? WcA : ((t == 1) ? WcM : WcT);
    int slot;
    if (t == g) slot = 0;
    else {
        int lower = (g == 0) ? 1 : 0;     // type that occupies slot 128
        slot = (t == lower) ? 128 : 192;
    }
    float* Mout = M9 + (size_t)b * 2048;
    for (int idx = threadIdx.x; idx < 2048; idx += 256) {
        int k = idx >> 4, j = idx & 15;
        float v;
        if (slot == 0) v = Wh[k * 16 + j];
        else {
            v = 0.f;
            for (int d = 0; d < kDC; d++)
                v += Wc[k * kDC + d] * Wh[(slot + d) * 16 + j];
        }
        Mout[idx] = v;
    }
}

// ---- hw1: HW1[n] = feat_type(n) @ WpW1_t; 8 rows/block x 128 cols ----
__global__ __launch_bounds__(128) void hw1_kernel(
    const float* __restrict__ hA, const float* __restrict__ hM,
    const float* __restrict__ hT, const float* __restrict__ WpW1,
    float* __restrict__ HW1)
{
    int b = blockIdx.x;
    const float *A, *W; int typeN, rowBase, lb;
    if (b < 545)       { lb = b;        A = hA; W = WpW1;              typeN = kNA; rowBase = 0; }
    else if (b < 1005) { lb = b - 545;  A = hM; W = WpW1 + 512 * 128;  typeN = kNM; rowBase = kNA; }
    else               { lb = b - 1005; A = hT; W = WpW1 + 1024 * 128; typeN = kNT; rowBase = kNA + kNM; }
    int r0 = lb * 8, col = threadIdx.x;
    float acc[8];
#pragma unroll
    for (int r = 0; r < 8; r++) acc[r] = 0.f;
    for (int k = 0; k < kDIN; k += 4) {
        float b0 = W[(k + 0) * kDE + col];
        float b1 = W[(k + 1) * kDE + col];
        float b2 = W[(k + 2) * kDE + col];
        float b3 = W[(k + 3) * kDE + col];
#pragma unroll
        for (int r = 0; r < 8; r++) {
            int gr = min(r0 + r, typeN - 1);                  // uniform -> s_load
            const float4 a4 = *(const float4*)(A + (size_t)gr * kDIN + k);
            acc[r] += a4.x * b0 + a4.y * b1 + a4.z * b2 + a4.w * b3;
        }
    }
#pragma unroll
    for (int r = 0; r < 8; r++) {
        int lr = r0 + r;
        if (lr < typeN) HW1[(size_t)(rowBase + lr) * kDE + col] = acc[r];
    }
}

// ---- CSR build (clamped) ----
__device__ __forceinline__ int clampN(int v) { return min(max(v, 0), kN - 1); }

__global__ __launch_bounds__(256) void hist_kernel(const int* __restrict__ key,
                                                   int* __restrict__ counts)
{
    int e = blockIdx.x * 256 + threadIdx.x;
    if (e < kE) atomicAdd(&counts[clampN(key[e])], 1);
}

__global__ __launch_bounds__(256) void scan_kernel(int* __restrict__ cnt_cur,
                                                   int* __restrict__ rowptr)
{
    __shared__ int sums[256];
    int tid = threadIdx.x;
    int i0 = tid * 63, i1 = min(i0 + 63, kN);
    int s = 0;
    for (int i = i0; i < i1; i++) s += cnt_cur[i];
    sums[tid] = s;
    __syncthreads();
    if (tid == 0) {
        int run = 0;
        for (int i = 0; i < 256; i++) { int v = sums[i]; sums[i] = run; run += v; }
    }
    __syncthreads();
    int base = sums[tid];
    for (int i = i0; i < i1; i++) {
        int c = cnt_cur[i];
        rowptr[i] = base;
        cnt_cur[i] = base;       // becomes fill cursor
        base += c;
    }
    if (tid == 0) rowptr[kN] = kE;
}

__global__ __launch_bounds__(256) void fill_kernel(const int* __restrict__ stored,
                                                   const int* __restrict__ key,
                                                   int* __restrict__ cursor,
                                                   int* __restrict__ esrc)
{
    int e = blockIdx.x * 256 + threadIdx.x;
    if (e < kE) {
        int p = atomicAdd(&cursor[clampN(key[e])], 1);
        esrc[min(p, kE - 1)] = clampN(stored[e]);
    }
}

// ---- agg1 fused: h1[n] = relu(sum_{e:dst==n} HW1[src[e]] + b1) ----
__global__ __launch_bounds__(kDE) void agg_relu_kernel(const float* __restrict__ X,
                                                       const int* __restrict__ rowptr,
                                                       const int* __restrict__ esrc,
                                                       const float* __restrict__ b1,
                                                       float* __restrict__ out)
{
    int n = blockIdx.x, tid = threadIdx.x;
    int j = rowptr[n], end = rowptr[n + 1];
    float acc0 = 0.f, acc1 = 0.f;
    for (; j + 1 < end; j += 2) {
        int s0 = esrc[j], s1 = esrc[j + 1];
        acc0 += X[(size_t)s0 * kDE + tid];
        acc1 += X[(size_t)s1 * kDE + tid];
    }
    if (j < end) acc0 += X[(size_t)esrc[j] * kDE + tid];
    out[(size_t)n * kDE + tid] = fmaxf(acc0 + acc1 + b1[tid], 0.f);
}

// ---- agg2: plain segment sum ----
__global__ __launch_bounds__(kDE) void agg_kernel(const float* __restrict__ X,
                                                  const int* __restrict__ rowptr,
                                                  const int* __restrict__ esrc,
                                                  float* __restrict__ out)
{
    int n = blockIdx.x, tid = threadIdx.x;
    int j = rowptr[n], end = rowptr[n + 1];
    float acc0 = 0.f, acc1 = 0.f;
    for (; j + 1 < end; j += 2) {
        int s0 = esrc[j], s1 = esrc[j + 1];
        acc0 += X[(size_t)s0 * kDE + tid];
        acc1 += X[(size_t)s1 * kDE + tid];
    }
    if (j < end) acc0 += X[(size_t)esrc[j] * kDE + tid];
    out[(size_t)n * kDE + tid] = acc0 + acc1;
}

// ---- gemm2: hn = agg2 @ W2 + b2 (128x128), 8 rows/block ----
__global__ __launch_bounds__(kDE) void gemm_bias_kernel(
    const float* __restrict__ X, const float* __restrict__ W,
    const float* __restrict__ bias, float* __restrict__ out)
{
    int r0 = blockIdx.x * 8;
    int col = threadIdx.x;
    float acc[8];
#pragma unroll
    for (int r = 0; r < 8; r++) acc[r] = 0.f;
    for (int k = 0; k < kDE; k += 4) {
        float b0 = W[(k + 0) * kDE + col];
        float b1 = W[(k + 1) * kDE + col];
        float b2 = W[(k + 2) * kDE + col];
        float b3 = W[(k + 3) * kDE + col];
#pragma unroll
        for (int r = 0; r < 8; r++) {
            int gr = min(r0 + r, kN - 1);                     // uniform -> s_load
            const float4 a4 = *(const float4*)(X + (size_t)gr * kDE + k);
            acc[r] += a4.x * b0 + a4.y * b1 + a4.z * b2 + a4.w * b3;
        }
    }
    float bv = bias[col];
#pragma unroll
    for (int r = 0; r < 8; r++) {
        int gr = r0 + r;
        if (gr < kN) out[(size_t)gr * kDE + col] = acc[r] + bv;
    }
}

// ---- row L2-normalize; write h + h_movie (f32 out) ----
__global__ __launch_bounds__(kDE) void norm_kernel(float* __restrict__ h2,
                                                   float* __restrict__ out)
{
    int n = blockIdx.x, tid = threadIdx.x;
    float v = h2[(size_t)n * kDE + tid];
    float ss = v * v;
#pragma unroll
    for (int o = 32; o > 0; o >>= 1) ss += __shfl_xor(ss, o);
    __shared__ float wsum[2];
    if ((tid & 63) == 0) wsum[tid >> 6] = ss;
    __syncthreads();
    float tot = wsum[0] + wsum[1];
    float sc = 1.f / fmaxf(sqrtf(tot), 1e-12f);
    float hv = v * sc;
    h2[(size_t)n * kDE + tid] = hv;
    out[(size_t)n * kDE + tid] = hv;
    if (n >= kNA && n < kNA + kNM)
        out[OUT_HM + (size_t)(n - kNA) * kDE + tid] = hv;
}

// ---- partial tables: P[g][n][16] = hn[n] @ M9[g][type(n)] ----
// grid = 3 groups x 2005 type-blocks; block = 8 rows x 16 cols
__global__ __launch_bounds__(128) void partial_kernel(const float* __restrict__ hn,
                                                      const float* __restrict__ M9,
                                                      float* __restrict__ P)
{
    int b = blockIdx.x;
    int g = b / 2005, b2 = b % 2005;
    int t, lb, typeN, rowBase;
    if (b2 < 545)       { t = 0; lb = b2;        typeN = kNA; rowBase = 0; }
    else if (b2 < 1005) { t = 1; lb = b2 - 545;  typeN = kNM; rowBase = kNA; }
    else                { t = 2; lb = b2 - 1005; typeN = kNT; rowBase = kNA + kNM; }
    const float* M = M9 + (size_t)(g * 3 + t) * 2048;
    int r = threadIdx.x >> 4, j = threadIdx.x & 15;
    int lr = lb * 8 + r;
    if (lr >= typeN) return;
    int n = rowBase + lr;
    float acc = 0.f;
    for (int k = 0; k < kDE; k += 4) {
        const float4 h4 = *(const float4*)(hn + (size_t)n * kDE + k);
        acc += h4.x * M[(k + 0) * 16 + j] + h4.y * M[(k + 1) * 16 + j]
             + h4.z * M[(k + 2) * 16 + j] + h4.w * M[(k + 3) * 16 + j];
    }
    P[((size_t)g * kN + n) * 16 + j] = acc;
}

// ---- classifier-lite: 3 x 16-float gathers + relu-dot + sigmoid ----
__global__ __launch_bounds__(256) void cls_lite_kernel(
    const float* __restrict__ P,
    const int* __restrict__ n0a, const int* __restrict__ n0m, const int* __restrict__ n0t,
    const int* __restrict__ n1a, const int* __restrict__ n1m, const int* __restrict__ n1t,
    const int* __restrict__ n2a, const int* __restrict__ n2m, const int* __restrict__ n2t,
    const float* __restrict__ WoA, const float* __restrict__ WoM, const float* __restrict__ WoT,
    float* __restrict__ out, int blocksPerGroup)
{
    int g = blockIdx.x / blocksPerGroup;
    int i = (blockIdx.x % blocksPerGroup) * 256 + threadIdx.x;
    if (i >= kS) return;
    auto cA = [](int v){ return min(max(v, 0), kNA - 1); };
    auto cM = [](int v){ return min(max(v, 0), kNM - 1); };
    auto cT = [](int v){ return min(max(v, 0), kNT - 1); };
    int ra, rb, rc;
    if (g == 0)      { ra = cA(n0a[i]);             rb = kNA + cM(n0m[i]);  rc = kNA + kNM + cT(n0t[i]); }
    else if (g == 1) { ra = kNA + cM(n1m[i]);       rb = cA(n1a[i]);        rc = kNA + kNM + cT(n1t[i]); }
    else             { ra = kNA + kNM + cT(n2t[i]); rb = cA(n2a[i]);        rc = kNA + cM(n2m[i]); }
    const float* Pg = P + (size_t)g * kN * 16;
    const float* wo = (g == 0) ? WoA : ((g == 1) ? WoM : WoT);   // uniform -> s_load
    const float4* pa = (const float4*)(Pg + (size_t)ra * 16);
    const float4* pb = (const float4*)(Pg + (size_t)rb * 16);
    const float4* pc = (const float4*)(Pg + (size_t)rc * 16);
    float p = 0.f;
#pragma unroll
    for (int q = 0; q < 4; q++) {
        float4 a = pa[q], b = pb[q], c = pc[q];
        p += fmaxf(a.x + b.x + c.x, 0.f) * wo[q * 4 + 0];
        p += fmaxf(a.y + b.y + c.y, 0.f) * wo[q * 4 + 1];
        p += fmaxf(a.z + b.z + c.z, 0.f) * wo[q * 4 + 2];
        p += fmaxf(a.w + b.w + c.w, 0.f) * wo[q * 4 + 3];
    }
    out[OUT_X + (size_t)g * kS + i] = 1.f / (1.f + expf(-p));
}

extern "C" void kernel_launch(void* const* d_in, const int* in_sizes, int n_in,
                              void* d_out, int out_size, void* d_ws, size_t ws_size,
                              hipStream_t stream)
{
    (void)out_size;
    // canary: verify input ordering/sizes; if wrong, launch nothing
    static const int expected[30] = {
        2228736, 1882112, 4096000, 131072, 131072, 131072, 32768, 128, 16384, 128,
        8192, 8192, 8192, 4096, 4096, 4096, 16, 16, 16,
        500000, 500000, 200000, 200000, 200000, 200000, 200000, 200000, 200000, 200000, 200000 };
    if (n_in != 30) return;
    for (int i = 0; i < 30; i++) if (in_sizes[i] != expected[i]) return;
    if (ws_size < WS_NEEDED) return;

    // inputs proven f32 / int32 (rounds 7-10)
    const float* h_a  = (const float*)d_in[0];
    const float* h_m  = (const float*)d_in[1];
    const float* h_t  = (const float*)d_in[2];
    const float* Wp_a = (const float*)d_in[3];
    const float* Wp_m = (const float*)d_in[4];
    const float* Wp_t = (const float*)d_in[5];
    const float* W1   = (const float*)d_in[6];
    const float* b1   = (const float*)d_in[7];
    const float* W2   = (const float*)d_in[8];
    const float* b2   = (const float*)d_in[9];
    const float* Wc_a = (const float*)d_in[10];
    const float* Wc_m = (const float*)d_in[11];
    const float* Wc_t = (const float*)d_in[12];
    const float* Wh_a = (const float*)d_in[13];
    const float* Wh_m = (const float*)d_in[14];
    const float* Wh_t = (const float*)d_in[15];
    const float* Wo_a = (const float*)d_in[16];
    const float* Wo_m = (const float*)d_in[17];
    const float* Wo_t = (const float*)d_in[18];
    const int* src = (const int*)d_in[19];
    const int* dst = (const int*)d_in[20];

    char* ws = (char*)d_ws;
    float* WpW1  = (float*)(ws + OFF_WPW1);
    float* M9    = (float*)(ws + OFF_M9);
    float* HW1   = (float*)(ws + OFF_HW1);
    float* h1    = (float*)(ws + OFF_H1);
    float* agg2  = (float*)(ws + OFF_AGG2);
    float* hn    = (float*)(ws + OFF_HN);
    float* P     = (float*)(ws + OFF_P);
    int* esrc    = (int*)(ws + OFF_ESRC);
    int* rowptr  = (int*)(ws + OFF_RP);
    int* cursor  = (int*)(ws + OFF_CUR);
    float* out   = (float*)d_out;

    hipMemsetAsync(cursor, 0, (size_t)kN * 4, stream);

    hist_kernel<<<dim3(1954), dim3(256), 0, stream>>>(dst, cursor);
    scan_kernel<<<dim3(1), dim3(256), 0, stream>>>(cursor, rowptr);
    fill_kernel<<<dim3(1954), dim3(256), 0, stream>>>(src, dst, cursor, esrc);

    prep1_kernel<<<dim3(384), dim3(128), 0, stream>>>(Wp_a, Wp_m, Wp_t, W1, WpW1);
    prep2_kernel<<<dim3(9), dim3(256), 0, stream>>>(Wh_a, Wh_m, Wh_t, Wc_a, Wc_m, Wc_t, M9);

    hw1_kernel<<<dim3(2005), dim3(128), 0, stream>>>(h_a, h_m, h_t, WpW1, HW1);
    agg_relu_kernel<<<dim3(kN), dim3(kDE), 0, stream>>>(HW1, rowptr, esrc, b1, h1);
    agg_kernel<<<dim3(kN), dim3(kDE), 0, stream>>>(h1, rowptr, esrc, agg2);
    gemm_bias_kernel<<<dim3(2004), dim3(kDE), 0, stream>>>(agg2, W2, b2, hn);
    norm_kernel<<<dim3(kN), dim3(kDE), 0, stream>>>(hn, out);
    partial_kernel<<<dim3(6015), dim3(128), 0, stream>>>(hn, M9, P);
    cls_lite_kernel<<<dim3(2346), dim3(256), 0, stream>>>(P,
        (const int*)d_in[21], (const int*)d_in[22], (const int*)d_in[23],
        (const int*)d_in[24], (const int*)d_in[25], (const int*)d_in[26],
        (const int*)d_in[27], (const int*)d_in[28], (const int*)d_in[29],
        Wo_a, Wo_m, Wo_t, out, 782);
}